// Round 1
// baseline (430.214 us; speedup 1.0000x reference)
//
#include <hip/hip_runtime.h>
#include <hip/hip_bf16.h>

#define GAS __attribute__((address_space(1)))
#define LAS __attribute__((address_space(3)))

typedef __attribute__((ext_vector_type(8))) short bf16x8;
typedef __attribute__((ext_vector_type(4))) float f32x4;

#define D_MODEL 1024
#define NHEADS 16
#define DK 64
#define BB 4
#define SS 2048

static __device__ __forceinline__ float b2f(unsigned short u) {
  union { unsigned int i; float f; } c; c.i = ((unsigned int)u) << 16; return c.f;
}
static __device__ __forceinline__ unsigned short f2b(float f) {
  union { float f; unsigned int i; } c; c.f = f;
  unsigned int x = c.i;
  x += 0x7fffu + ((x >> 16) & 1u);   // RNE
  return (unsigned short)(x >> 16);
}

// ---------------- cast f32 -> bf16 (vectorized float4 -> ushort4) ----------
__global__ __launch_bounds__(256) void cast_kernel(const float* __restrict__ in,
                                                   unsigned short* __restrict__ out,
                                                   int n4) {
  int i = blockIdx.x * 256 + threadIdx.x;
  if (i >= n4) return;
  float4 v = reinterpret_cast<const float4*>(in)[i];
  ushort4 o;
  o.x = f2b(v.x); o.y = f2b(v.y); o.z = f2b(v.z); o.w = f2b(v.w);
  reinterpret_cast<ushort4*>(out)[i] = o;
}

// ---------------- bf16 GEMM, C = A (M x K) * B^T (N x K), K = 1024 --------
// 128x128 tile, 4 waves (2x2), each wave 64x64 = 4x4 frags of 16x16x32 MFMA.
// EPI=0: write f32 row-major [M][N].  EPI=1: scatter bf16 into QKV head layout.
static __device__ __forceinline__ void gl_lds16(const void* g, void* l) {
  __builtin_amdgcn_global_load_lds((const GAS unsigned int*)g,
                                   (LAS unsigned int*)l, 16, 0, 0);
}

template <int EPI>
__global__ __launch_bounds__(256) void gemm_bt(const unsigned short* __restrict__ A,
                                               const unsigned short* __restrict__ Bw,
                                               void* __restrict__ outp, int N) {
  const int K = 1024;
  __shared__ unsigned short lds_a[128 * 32];
  __shared__ unsigned short lds_b[128 * 32];
  int t = threadIdx.x;
  int lane = t & 63;
  int w = t >> 6, wr = w >> 1, wc = w & 1;
  int la = lane & 15, lg = lane >> 4;
  int rowBase = blockIdx.x * 128;
  int colBase = blockIdx.y * 128;
  const unsigned short* Ab = A + (size_t)(rowBase + (t >> 2)) * K + (t & 3) * 8;
  const unsigned short* Bb = Bw + (size_t)(colBase + (t >> 2)) * K + (t & 3) * 8;

  f32x4 acc[4][4];
#pragma unroll
  for (int i = 0; i < 4; ++i)
#pragma unroll
    for (int j = 0; j < 4; ++j) acc[i][j] = (f32x4){0.f, 0.f, 0.f, 0.f};

  for (int k0 = 0; k0 < K; k0 += 32) {
    gl_lds16(Ab + k0, &lds_a[t * 8]);
    gl_lds16(Ab + (size_t)64 * K + k0, &lds_a[2048 + t * 8]);
    gl_lds16(Bb + k0, &lds_b[t * 8]);
    gl_lds16(Bb + (size_t)64 * K + k0, &lds_b[2048 + t * 8]);
    __syncthreads();
    bf16x8 af[4], bfr[4];
#pragma unroll
    for (int mi = 0; mi < 4; ++mi)
      af[mi] = *reinterpret_cast<const bf16x8*>(&lds_a[(wr * 64 + mi * 16 + la) * 32 + lg * 8]);
#pragma unroll
    for (int ni = 0; ni < 4; ++ni)
      bfr[ni] = *reinterpret_cast<const bf16x8*>(&lds_b[(wc * 64 + ni * 16 + la) * 32 + lg * 8]);
#pragma unroll
    for (int mi = 0; mi < 4; ++mi)
#pragma unroll
      for (int ni = 0; ni < 4; ++ni)
        acc[mi][ni] = __builtin_amdgcn_mfma_f32_16x16x32_bf16(af[mi], bfr[ni], acc[mi][ni], 0, 0, 0);
    __syncthreads();
  }

  if (EPI == 0) {
    float* out = (float*)outp;
#pragma unroll
    for (int mi = 0; mi < 4; ++mi)
#pragma unroll
      for (int ni = 0; ni < 4; ++ni)
#pragma unroll
        for (int j = 0; j < 4; ++j) {
          int row = rowBase + wr * 64 + mi * 16 + lg * 4 + j;
          int col = colBase + wc * 64 + ni * 16 + la;
          out[(size_t)row * N + col] = acc[mi][ni][j];
        }
  } else {
    // col in [0,3072): which = col>>10 (0=Q,1=K,2=V); within: h = (col&1023)>>6, dd = col&63
    // row = b*2048+s.  dst[which*8388608 + ((b*16+h)*2048+s)*64 + dd]
    unsigned short* qkv = (unsigned short*)outp;
#pragma unroll
    for (int mi = 0; mi < 4; ++mi)
#pragma unroll
      for (int ni = 0; ni < 4; ++ni)
#pragma unroll
        for (int j = 0; j < 4; ++j) {
          int row = rowBase + wr * 64 + mi * 16 + lg * 4 + j;
          int col = colBase + wc * 64 + ni * 16 + la;
          int which = col >> 10, d = col & 1023;
          int h = d >> 6, dd = d & 63;
          int b = row >> 11, s = row & 2047;
          size_t off = (size_t)which * 8388608 +
                       ((size_t)(b * NHEADS + h) * SS + s) * DK + dd;
          qkv[off] = f2b(acc[mi][ni][j]);
        }
  }
}

// ---------------- RoPE in-place on Q and K (b,h,s,d) bf16 ------------------
// pair pr in [0,32): angle = pos[s] * theta^(-pr/32)
__global__ __launch_bounds__(256) void rope_kernel(unsigned short* __restrict__ Q,
                                                   unsigned short* __restrict__ Kk,
                                                   const int* __restrict__ pos) {
  int i = blockIdx.x * 256 + threadIdx.x;  // < 2 * 64 * 2048 * 32 = 8388608
  int pr = i & 31;
  int row = (i >> 5) & 131071;  // bh*2048 + s
  unsigned short* base = (i >> 22) ? Kk : Q;
  int s = row & 2047;
  float p = (float)pos[s];
  // ln(10000)/32 = 0.287823136624...
  float ang = p * __expf(-(float)pr * 0.2878231366242557f);
  float sn, cs;
  sincosf(ang, &sn, &cs);
  unsigned int* pp = reinterpret_cast<unsigned int*>(base + (size_t)row * 64 + pr * 2);
  unsigned int v = *pp;
  float x1 = b2f((unsigned short)(v & 0xffffu));
  float x2 = b2f((unsigned short)(v >> 16));
  float r1 = x1 * cs - x2 * sn;
  float r2 = x1 * sn + x2 * cs;
  *pp = (unsigned int)f2b(r1) | ((unsigned int)f2b(r2) << 16);
}

// ---------------- flash attention, causal, bf16 ----------------------------
// grid (S/64, B*H); block 256 = 4 waves, wave w owns q-rows [qBase+16w, +16)
__global__ __launch_bounds__(256) void attn_kernel(const unsigned short* __restrict__ Qh,
                                                   const unsigned short* __restrict__ Kh,
                                                   const unsigned short* __restrict__ Vh,
                                                   unsigned short* __restrict__ outA) {
  __shared__ unsigned short vt[64 * 72];        // V^T[d][key], stride 72 (16B-aligned rows)
  __shared__ unsigned short plds[4][16 * 72];   // per-wave P[q][key]
  int qt = blockIdx.x, bh = blockIdx.y;
  int t = threadIdx.x, lane = t & 63, w = t >> 6;
  int la = lane & 15, lg = lane >> 4;
  int qBase = qt * 64;
  const unsigned short* Qp = Qh + (size_t)bh * SS * DK;
  const unsigned short* Kp = Kh + (size_t)bh * SS * DK;
  const unsigned short* Vp = Vh + (size_t)bh * SS * DK;

  int qrow = qBase + w * 16 + la;
  bf16x8 qf0 = *reinterpret_cast<const bf16x8*>(Qp + (size_t)qrow * 64 + lg * 8);
  bf16x8 qf1 = *reinterpret_cast<const bf16x8*>(Qp + (size_t)qrow * 64 + 32 + lg * 8);

  f32x4 o[4];
#pragma unroll
  for (int i = 0; i < 4; ++i) o[i] = (f32x4){0.f, 0.f, 0.f, 0.f};
  float m[4] = {-1e30f, -1e30f, -1e30f, -1e30f};
  float l[4] = {0.f, 0.f, 0.f, 0.f};

  int nkv = qt + 1;
  for (int kv = 0; kv < nkv; ++kv) {
    int kvBase = kv * 64;
    __syncthreads();  // previous iter's vt/plds reads done before restage
    // stage V^T: 64 keys x 64 d, writes contiguous across lanes (key fastest)
    for (int c = t; c < 512; c += 256) {
      int key = c & 63, d0 = (c >> 6) * 8;
      bf16x8 vv = *reinterpret_cast<const bf16x8*>(Vp + (size_t)(kvBase + key) * 64 + d0);
#pragma unroll
      for (int j = 0; j < 8; ++j) vt[(d0 + j) * 72 + key] = (unsigned short)vv[j];
    }
    __syncthreads();

    // S = Q K^T  (16q x 64key per wave), K frags direct from global (16B/lane)
    f32x4 sf[4];
#pragma unroll
    for (int nb = 0; nb < 4; ++nb) {
      int key = kvBase + nb * 16 + la;
      const unsigned short* kp = Kp + (size_t)key * 64 + lg * 8;
      bf16x8 k0 = *reinterpret_cast<const bf16x8*>(kp);
      bf16x8 k1 = *reinterpret_cast<const bf16x8*>(kp + 32);
      f32x4 s = (f32x4){0.f, 0.f, 0.f, 0.f};
      s = __builtin_amdgcn_mfma_f32_16x16x32_bf16(qf0, k0, s, 0, 0, 0);
      s = __builtin_amdgcn_mfma_f32_16x16x32_bf16(qf1, k1, s, 0, 0, 0);
      sf[nb] = s;
    }

    // online softmax; C-frag: row = lg*4+j (q), col = la (key within nb block)
#pragma unroll
    for (int j = 0; j < 4; ++j) {
      int q = qBase + w * 16 + lg * 4 + j;
      float sv[4];
#pragma unroll
      for (int nb = 0; nb < 4; ++nb) {
        float v = sf[nb][j] * 0.125f;
        int key = kvBase + nb * 16 + la;
        if (key > q) v = -1e30f;  // causal mask (only bites on diagonal tile)
        sv[nb] = v;
      }
      float mx = fmaxf(fmaxf(sv[0], sv[1]), fmaxf(sv[2], sv[3]));
#pragma unroll
      for (int d = 1; d < 16; d <<= 1) mx = fmaxf(mx, __shfl_xor(mx, d));
      float mnew = fmaxf(m[j], mx);
      float corr = __expf(m[j] - mnew);
      float rs = 0.f;
      unsigned short pb[4];
#pragma unroll
      for (int nb = 0; nb < 4; ++nb) {
        float p = __expf(sv[nb] - mnew);
        rs += p;
        pb[nb] = f2b(p);
      }
#pragma unroll
      for (int d = 1; d < 16; d <<= 1) rs += __shfl_xor(rs, d);
      l[j] = l[j] * corr + rs;
      m[j] = mnew;
      int r = lg * 4 + j;
#pragma unroll
      for (int nb = 0; nb < 4; ++nb) plds[w][r * 72 + nb * 16 + la] = pb[nb];
#pragma unroll
      for (int db = 0; db < 4; ++db) o[db][j] *= corr;
    }
    __syncthreads();  // order plds writes before cross-lane reads

    // O += P V : A = P[q=la][key 8-contig], B = V[key][d=la] via vt rows
#pragma unroll
    for (int kk = 0; kk < 2; ++kk) {
      bf16x8 pa = *reinterpret_cast<const bf16x8*>(&plds[w][la * 72 + kk * 32 + lg * 8]);
#pragma unroll
      for (int db = 0; db < 4; ++db) {
        bf16x8 vb = *reinterpret_cast<const bf16x8*>(&vt[(db * 16 + la) * 72 + kk * 32 + lg * 8]);
        o[db] = __builtin_amdgcn_mfma_f32_16x16x32_bf16(pa, vb, o[db], 0, 0, 0);
      }
    }
  }

  // epilogue: normalize, write bf16 to (b, s, h*64+d) for final GEMM
  int b = bh >> 4, h = bh & 15;
#pragma unroll
  for (int db = 0; db < 4; ++db)
#pragma unroll
    for (int j = 0; j < 4; ++j) {
      int q = qBase + w * 16 + lg * 4 + j;
      float val = o[db][j] / l[j];
      size_t off = ((size_t)(b * SS + q)) * D_MODEL + h * DK + db * 16 + la;
      outA[off] = f2b(val);
    }
}

extern "C" void kernel_launch(void* const* d_in, const int* in_sizes, int n_in,
                              void* d_out, int out_size, void* d_ws, size_t ws_size,
                              hipStream_t stream) {
  (void)in_sizes; (void)n_in; (void)out_size; (void)ws_size;
  const float* x  = (const float*)d_in[0];
  const float* Wq = (const float*)d_in[1];
  const float* Wk = (const float*)d_in[2];
  const float* Wv = (const float*)d_in[3];
  const float* Wo = (const float*)d_in[4];
  const int* pos  = (const int*)d_in[5];

  char* ws = (char*)d_ws;
  unsigned short* xb    = (unsigned short*)(ws);               // 16 MB: x bf16 [8192][1024]
  unsigned short* Wcat  = (unsigned short*)(ws + 16777216);    // 6 MB: Wq|Wk|Wv rows [3072][1024]
  unsigned short* Wob   = (unsigned short*)(ws + 23068672);    // 2 MB
  unsigned short* Qh    = (unsigned short*)(ws + 25165824);    // 3 x 16 MB: Q,K,V (b,h,s,d)
  unsigned short* attnO = (unsigned short*)(ws + 75497472);    // 16 MB: (b,s,1024) bf16

  cast_kernel<<<8192, 256, 0, stream>>>(x, xb, 2097152);
  cast_kernel<<<1024, 256, 0, stream>>>(Wq, Wcat, 262144);
  cast_kernel<<<1024, 256, 0, stream>>>(Wk, Wcat + 1048576, 262144);
  cast_kernel<<<1024, 256, 0, stream>>>(Wv, Wcat + 2097152, 262144);
  cast_kernel<<<1024, 256, 0, stream>>>(Wo, Wob, 262144);

  gemm_bt<1><<<dim3(64, 24), 256, 0, stream>>>(xb, Wcat, Qh, 3072);
  rope_kernel<<<32768, 256, 0, stream>>>(Qh, Qh + 8388608, pos);
  attn_kernel<<<dim3(32, 64), 256, 0, stream>>>(Qh, Qh + 8388608, Qh + 16777216, attnO);
  gemm_bt<0><<<dim3(64, 8), 256, 0, stream>>>(attnO, Wob, (float*)d_out, 1024);
}

// Round 2
// 311.001 us; speedup vs baseline: 1.3833x; 1.3833x over previous
//
#include <hip/hip_runtime.h>
#include <hip/hip_bf16.h>

#define GAS __attribute__((address_space(1)))
#define LAS __attribute__((address_space(3)))

typedef __attribute__((ext_vector_type(8))) short bf16x8;
typedef __attribute__((ext_vector_type(4))) float f32x4;

#define D_MODEL 1024
#define NHEADS 16
#define DK 64
#define BB 4
#define SS 2048

static __device__ __forceinline__ float b2f(unsigned short u) {
  union { unsigned int i; float f; } c; c.i = ((unsigned int)u) << 16; return c.f;
}
static __device__ __forceinline__ unsigned short f2b(float f) {
  union { float f; unsigned int i; } c; c.f = f;
  unsigned int x = c.i;
  x += 0x7fffu + ((x >> 16) & 1u);   // RNE
  return (unsigned short)(x >> 16);
}

// ---------------- cast f32 -> bf16 (vectorized float4 -> ushort4) ----------
__global__ __launch_bounds__(256) void cast_kernel(const float* __restrict__ in,
                                                   unsigned short* __restrict__ out,
                                                   int n4) {
  int i = blockIdx.x * 256 + threadIdx.x;
  if (i >= n4) return;
  float4 v = reinterpret_cast<const float4*>(in)[i];
  ushort4 o;
  o.x = f2b(v.x); o.y = f2b(v.y); o.z = f2b(v.z); o.w = f2b(v.w);
  reinterpret_cast<ushort4*>(out)[i] = o;
}

// ---------------- bf16 GEMM, C = A (M x K) * B^T (N x K), K = 1024 --------
// 128x128 tile, 4 waves (2x2), each wave 64x64 = 4x4 frags of 16x16x32 MFMA.
// EPI=0: write f32 row-major [M][N].  EPI=1: scatter bf16 into QKV head
// layout; V is stored TRANSPOSED per head ([b,h,d,s]) for attention staging.
static __device__ __forceinline__ void gl_lds16(const void* g, void* l) {
  __builtin_amdgcn_global_load_lds((const GAS unsigned int*)g,
                                   (LAS unsigned int*)l, 16, 0, 0);
}

template <int EPI>
__global__ __launch_bounds__(256) void gemm_bt(const unsigned short* __restrict__ A,
                                               const unsigned short* __restrict__ Bw,
                                               void* __restrict__ outp, int N) {
  const int K = 1024;
  __shared__ unsigned short lds_a[128 * 32];
  __shared__ unsigned short lds_b[128 * 32];
  int t = threadIdx.x;
  int lane = t & 63;
  int w = t >> 6, wr = w >> 1, wc = w & 1;
  int la = lane & 15, lg = lane >> 4;
  int rowBase = blockIdx.x * 128;
  int colBase = blockIdx.y * 128;
  const unsigned short* Ab = A + (size_t)(rowBase + (t >> 2)) * K + (t & 3) * 8;
  const unsigned short* Bb = Bw + (size_t)(colBase + (t >> 2)) * K + (t & 3) * 8;

  f32x4 acc[4][4];
#pragma unroll
  for (int i = 0; i < 4; ++i)
#pragma unroll
    for (int j = 0; j < 4; ++j) acc[i][j] = (f32x4){0.f, 0.f, 0.f, 0.f};

  for (int k0 = 0; k0 < K; k0 += 32) {
    gl_lds16(Ab + k0, &lds_a[t * 8]);
    gl_lds16(Ab + (size_t)64 * K + k0, &lds_a[2048 + t * 8]);
    gl_lds16(Bb + k0, &lds_b[t * 8]);
    gl_lds16(Bb + (size_t)64 * K + k0, &lds_b[2048 + t * 8]);
    __syncthreads();
    bf16x8 af[4], bfr[4];
#pragma unroll
    for (int mi = 0; mi < 4; ++mi)
      af[mi] = *reinterpret_cast<const bf16x8*>(&lds_a[(wr * 64 + mi * 16 + la) * 32 + lg * 8]);
#pragma unroll
    for (int ni = 0; ni < 4; ++ni)
      bfr[ni] = *reinterpret_cast<const bf16x8*>(&lds_b[(wc * 64 + ni * 16 + la) * 32 + lg * 8]);
#pragma unroll
    for (int mi = 0; mi < 4; ++mi)
#pragma unroll
      for (int ni = 0; ni < 4; ++ni)
        acc[mi][ni] = __builtin_amdgcn_mfma_f32_16x16x32_bf16(af[mi], bfr[ni], acc[mi][ni], 0, 0, 0);
    __syncthreads();
  }

  if (EPI == 0) {
    float* out = (float*)outp;
#pragma unroll
    for (int mi = 0; mi < 4; ++mi)
#pragma unroll
      for (int ni = 0; ni < 4; ++ni)
#pragma unroll
        for (int j = 0; j < 4; ++j) {
          int row = rowBase + wr * 64 + mi * 16 + lg * 4 + j;
          int col = colBase + wc * 64 + ni * 16 + la;
          out[(size_t)row * N + col] = acc[mi][ni][j];
        }
  } else {
    // col in [0,3072): which = col>>10 (0=Q,1=K,2=V); within: h = (col&1023)>>6, dd = col&63
    // row = b*2048+s.  Q,K: [which][b,h,s,d].  V: transposed [b,h,d,s].
    unsigned short* qkv = (unsigned short*)outp;
#pragma unroll
    for (int mi = 0; mi < 4; ++mi)
#pragma unroll
      for (int ni = 0; ni < 4; ++ni)
#pragma unroll
        for (int j = 0; j < 4; ++j) {
          int row = rowBase + wr * 64 + mi * 16 + lg * 4 + j;
          int col = colBase + wc * 64 + ni * 16 + la;
          int which = col >> 10, d = col & 1023;
          int h = d >> 6, dd = d & 63;
          int b = row >> 11, s = row & 2047;
          size_t off;
          if (which == 2)
            off = (size_t)2 * 8388608 +
                  ((size_t)(b * NHEADS + h) * DK + dd) * SS + s;
          else
            off = (size_t)which * 8388608 +
                  ((size_t)(b * NHEADS + h) * SS + s) * DK + dd;
          qkv[off] = f2b(acc[mi][ni][j]);
        }
  }
}

// ---------------- RoPE in-place on Q and K (b,h,s,d) bf16 ------------------
__global__ __launch_bounds__(256) void rope_kernel(unsigned short* __restrict__ Q,
                                                   unsigned short* __restrict__ Kk,
                                                   const int* __restrict__ pos) {
  int i = blockIdx.x * 256 + threadIdx.x;  // < 2 * 64 * 2048 * 32 = 8388608
  int pr = i & 31;
  int row = (i >> 5) & 131071;  // bh*2048 + s
  unsigned short* base = (i >> 22) ? Kk : Q;
  int s = row & 2047;
  float p = (float)pos[s];
  float ang = p * __expf(-(float)pr * 0.2878231366242557f);  // ln(1e4)/32
  float sn, cs;
  sincosf(ang, &sn, &cs);
  unsigned int* pp = reinterpret_cast<unsigned int*>(base + (size_t)row * 64 + pr * 2);
  unsigned int v = *pp;
  float x1 = b2f((unsigned short)(v & 0xffffu));
  float x2 = b2f((unsigned short)(v >> 16));
  float r1 = x1 * cs - x2 * sn;
  float r2 = x1 * sn + x2 * cs;
  *pp = (unsigned int)f2b(r1) | ((unsigned int)f2b(r2) << 16);
}

// ---------------- flash attention v2: causal, bf16, paired q-tiles ---------
// grid (16, B*H); block 256 = 4 waves. Block p handles q-tiles qtA=p and
// qtB=31-p (64 rows each) -> constant 33 tile-computations per block, shared
// K/V staging (tile A's KV range is a subset of tile B's).
// K tile [64 key][64 d] and V^T tile [64 d][64 key] staged via global_load_lds
// (linear LDS dest) with XOR-swizzled global SOURCE; reads apply the same
// swizzle: chunk' = chunk ^ (row&7)  (both-sides involution, rule #21).
#define SM_SCALE 0.18033688011112042f  /* 1/sqrt(64) * log2(e) */

static __device__ __forceinline__ void attn_tile(
    const unsigned short* __restrict__ kt, const unsigned short* __restrict__ vt,
    unsigned short* __restrict__ pl, int la, int lg,
    int qrow0, int kvBase, bool diag,
    bf16x8 q0, bf16x8 q1, float* m, float* l, f32x4* o) {
  // S = Q K^T  (16 q x 64 key)
  f32x4 sf[4];
#pragma unroll
  for (int nb = 0; nb < 4; ++nb) {
    int krow = nb * 16 + la;
    bf16x8 k0 = *reinterpret_cast<const bf16x8*>(&kt[krow * 64 + ((lg ^ (krow & 7)) << 3)]);
    bf16x8 k1 = *reinterpret_cast<const bf16x8*>(&kt[krow * 64 + (((4 + lg) ^ (krow & 7)) << 3)]);
    f32x4 s = (f32x4){0.f, 0.f, 0.f, 0.f};
    s = __builtin_amdgcn_mfma_f32_16x16x32_bf16(q0, k0, s, 0, 0, 0);
    s = __builtin_amdgcn_mfma_f32_16x16x32_bf16(q1, k1, s, 0, 0, 0);
    sf[nb] = s;
  }
  // online softmax in exp2 domain
#pragma unroll
  for (int j = 0; j < 4; ++j) {
    int q = qrow0 + lg * 4 + j;
    float sv[4];
#pragma unroll
    for (int nb = 0; nb < 4; ++nb) {
      float v = sf[nb][j] * SM_SCALE;
      if (diag && (kvBase + nb * 16 + la) > q) v = -1e30f;
      sv[nb] = v;
    }
    float mx = fmaxf(fmaxf(sv[0], sv[1]), fmaxf(sv[2], sv[3]));
#pragma unroll
    for (int d = 1; d < 16; d <<= 1) mx = fmaxf(mx, __shfl_xor(mx, d));
    float mnew = fmaxf(m[j], mx);
    float corr = exp2f(m[j] - mnew);
    float rs = 0.f;
    unsigned short pb[4];
#pragma unroll
    for (int nb = 0; nb < 4; ++nb) {
      float pv = exp2f(sv[nb] - mnew);
      rs += pv;
      pb[nb] = f2b(pv);
    }
#pragma unroll
    for (int d = 1; d < 16; d <<= 1) rs += __shfl_xor(rs, d);
    l[j] = l[j] * corr + rs;
    m[j] = mnew;
    int r = lg * 4 + j;
#pragma unroll
    for (int nb = 0; nb < 4; ++nb) pl[r * 72 + nb * 16 + la] = pb[nb];
#pragma unroll
    for (int db = 0; db < 4; ++db) o[db][j] *= corr;
  }
  // O += P V  (wave-local P in LDS; compiler-inserted lgkmcnt orders RAW)
#pragma unroll
  for (int kk = 0; kk < 2; ++kk) {
    bf16x8 pa = *reinterpret_cast<const bf16x8*>(&pl[la * 72 + kk * 32 + lg * 8]);
#pragma unroll
    for (int db = 0; db < 4; ++db) {
      int vrow = db * 16 + la;
      bf16x8 vb = *reinterpret_cast<const bf16x8*>(&vt[vrow * 64 + (((kk * 4 + lg) ^ (vrow & 7)) << 3)]);
      o[db] = __builtin_amdgcn_mfma_f32_16x16x32_bf16(pa, vb, o[db], 0, 0, 0);
    }
  }
}

__global__ __launch_bounds__(256) void attn_kernel(const unsigned short* __restrict__ Qh,
                                                   const unsigned short* __restrict__ Kh,
                                                   const unsigned short* __restrict__ Vt,
                                                   unsigned short* __restrict__ outA) {
  __shared__ unsigned short kt[64 * 64];
  __shared__ unsigned short vt[64 * 64];
  __shared__ unsigned short plds[4][16 * 72];
  int p = blockIdx.x, bh = blockIdx.y;
  int qtA = p, qtB = 31 - p;
  int t = threadIdx.x, lane = t & 63, w = t >> 6;
  int la = lane & 15, lg = lane >> 4;
  const unsigned short* Qp = Qh + (size_t)bh * SS * DK;
  const unsigned short* Kp = Kh + (size_t)bh * SS * DK;
  const unsigned short* Vtp = Vt + (size_t)bh * DK * SS;
  unsigned short* plw = plds[w];

  int qrA = qtA * 64 + w * 16;
  int qrB = qtB * 64 + w * 16;
  bf16x8 qA0 = *reinterpret_cast<const bf16x8*>(Qp + (size_t)(qrA + la) * 64 + lg * 8);
  bf16x8 qA1 = *reinterpret_cast<const bf16x8*>(Qp + (size_t)(qrA + la) * 64 + 32 + lg * 8);
  bf16x8 qB0 = *reinterpret_cast<const bf16x8*>(Qp + (size_t)(qrB + la) * 64 + lg * 8);
  bf16x8 qB1 = *reinterpret_cast<const bf16x8*>(Qp + (size_t)(qrB + la) * 64 + 32 + lg * 8);

  f32x4 oA[4], oB[4];
#pragma unroll
  for (int i = 0; i < 4; ++i) {
    oA[i] = (f32x4){0.f, 0.f, 0.f, 0.f};
    oB[i] = (f32x4){0.f, 0.f, 0.f, 0.f};
  }
  float mA[4] = {-1e30f, -1e30f, -1e30f, -1e30f}, lA[4] = {0.f, 0.f, 0.f, 0.f};
  float mB[4] = {-1e30f, -1e30f, -1e30f, -1e30f}, lB[4] = {0.f, 0.f, 0.f, 0.f};

  int c8 = t & 7;
  for (int kv = 0; kv <= qtB; ++kv) {
    int kvBase = kv * 64;
    __syncthreads();  // all waves done reading kt/vt
#pragma unroll
    for (int i = 0; i < 2; ++i) {
      int r = (t >> 3) + i * 32;
      gl_lds16(Kp + (size_t)(kvBase + r) * 64 + ((c8 ^ (r & 7)) << 3), &kt[t * 8 + i * 2048]);
      gl_lds16(Vtp + (size_t)r * SS + kvBase + ((c8 ^ (r & 7)) << 3), &vt[t * 8 + i * 2048]);
    }
    __syncthreads();  // staging complete

    attn_tile(kt, vt, plw, la, lg, qrB, kvBase, kv == qtB, qB0, qB1, mB, lB, oB);
    if (kv <= qtA)
      attn_tile(kt, vt, plw, la, lg, qrA, kvBase, kv == qtA, qA0, qA1, mA, lA, oA);
  }

  // epilogue: normalize, write bf16 to (b, s, h*64+d) for final GEMM
  int b = bh >> 4, h = bh & 15;
#pragma unroll
  for (int db = 0; db < 4; ++db)
#pragma unroll
    for (int j = 0; j < 4; ++j) {
      int qB_ = qrB + lg * 4 + j;
      size_t offB = ((size_t)(b * SS + qB_)) * D_MODEL + h * DK + db * 16 + la;
      outA[offB] = f2b(oB[db][j] / lB[j]);
      int qA_ = qrA + lg * 4 + j;
      size_t offA = ((size_t)(b * SS + qA_)) * D_MODEL + h * DK + db * 16 + la;
      outA[offA] = f2b(oA[db][j] / lA[j]);
    }
}

extern "C" void kernel_launch(void* const* d_in, const int* in_sizes, int n_in,
                              void* d_out, int out_size, void* d_ws, size_t ws_size,
                              hipStream_t stream) {
  (void)in_sizes; (void)n_in; (void)out_size; (void)ws_size;
  const float* x  = (const float*)d_in[0];
  const float* Wq = (const float*)d_in[1];
  const float* Wk = (const float*)d_in[2];
  const float* Wv = (const float*)d_in[3];
  const float* Wo = (const float*)d_in[4];
  const int* pos  = (const int*)d_in[5];

  char* ws = (char*)d_ws;
  unsigned short* xb    = (unsigned short*)(ws);               // 16 MB: x bf16 [8192][1024]
  unsigned short* Wcat  = (unsigned short*)(ws + 16777216);    // 6 MB: Wq|Wk|Wv rows [3072][1024]
  unsigned short* Wob   = (unsigned short*)(ws + 23068672);    // 2 MB
  unsigned short* Qh    = (unsigned short*)(ws + 25165824);    // Q,K (b,h,s,d); V^T (b,h,d,s)
  unsigned short* attnO = (unsigned short*)(ws + 75497472);    // 16 MB: (b,s,1024) bf16

  cast_kernel<<<8192, 256, 0, stream>>>(x, xb, 2097152);
  cast_kernel<<<1024, 256, 0, stream>>>(Wq, Wcat, 262144);
  cast_kernel<<<1024, 256, 0, stream>>>(Wk, Wcat + 1048576, 262144);
  cast_kernel<<<1024, 256, 0, stream>>>(Wv, Wcat + 2097152, 262144);
  cast_kernel<<<1024, 256, 0, stream>>>(Wo, Wob, 262144);

  gemm_bt<1><<<dim3(64, 24), 256, 0, stream>>>(xb, Wcat, Qh, 3072);
  rope_kernel<<<32768, 256, 0, stream>>>(Qh, Qh + 8388608, pos);
  attn_kernel<<<dim3(16, 64), 256, 0, stream>>>(Qh, Qh + 8388608, Qh + 16777216, attnO);
  gemm_bt<0><<<dim3(64, 8), 256, 0, stream>>>(attnO, Wob, (float*)d_out, 1024);
}

// Round 4
// 264.466 us; speedup vs baseline: 1.6267x; 1.1760x over previous
//
#include <hip/hip_runtime.h>
#include <hip/hip_bf16.h>

#define GAS __attribute__((address_space(1)))
#define LAS __attribute__((address_space(3)))

typedef __attribute__((ext_vector_type(8))) short bf16x8;
typedef __attribute__((ext_vector_type(4))) float f32x4;

#define D_MODEL 1024
#define NHEADS 16
#define DK 64
#define BB 4
#define SS 2048

#define SM_SCALE 0.18033688011112042f  /* 1/sqrt(64) * log2(e), folded into Q at RoPE */

static __device__ __forceinline__ float b2f(unsigned short u) {
  union { unsigned int i; float f; } c; c.i = ((unsigned int)u) << 16; return c.f;
}
static __device__ __forceinline__ unsigned short f2b(float f) {
  union { float f; unsigned int i; } c; c.f = f;
  unsigned int x = c.i;
  x += 0x7fffu + ((x >> 16) & 1u);   // RNE
  return (unsigned short)(x >> 16);
}

// ---------------- cast f32 -> bf16 (vectorized float4 -> ushort4) ----------
__global__ __launch_bounds__(256) void cast_kernel(const float* __restrict__ in,
                                                   unsigned short* __restrict__ out,
                                                   int n4) {
  int i = blockIdx.x * 256 + threadIdx.x;
  if (i >= n4) return;
  float4 v = reinterpret_cast<const float4*>(in)[i];
  ushort4 o;
  o.x = f2b(v.x); o.y = f2b(v.y); o.z = f2b(v.z); o.w = f2b(v.w);
  reinterpret_cast<ushort4*>(out)[i] = o;
}

// all 4 weight matrices in one launch; dst regions are contiguous in ws
__global__ __launch_bounds__(256) void cast4_kernel(const float* __restrict__ a,
                                                    const float* __restrict__ b,
                                                    const float* __restrict__ c,
                                                    const float* __restrict__ d,
                                                    unsigned short* __restrict__ out) {
  int i = blockIdx.x * 256 + threadIdx.x;  // < 4 * 262144
  int which = i >> 18, off = i & 0x3ffff;
  const float* src = which == 0 ? a : which == 1 ? b : which == 2 ? c : d;
  float4 v = reinterpret_cast<const float4*>(src)[off];
  ushort4 o;
  o.x = f2b(v.x); o.y = f2b(v.y); o.z = f2b(v.z); o.w = f2b(v.w);
  reinterpret_cast<ushort4*>(out)[i] = o;
}

// ---------------- bf16 GEMM, C = A (M x K) * B^T (N x K), K = 1024 --------
static __device__ __forceinline__ void gl_lds16(const void* g, void* l) {
  __builtin_amdgcn_global_load_lds((const GAS unsigned int*)g,
                                   (LAS unsigned int*)l, 16, 0, 0);
}

template <int EPI>
__global__ __launch_bounds__(256) void gemm_bt(const unsigned short* __restrict__ A,
                                               const unsigned short* __restrict__ Bw,
                                               void* __restrict__ outp, int N) {
  const int K = 1024;
  __shared__ unsigned short lds_a[128 * 32];
  __shared__ unsigned short lds_b[128 * 32];
  int t = threadIdx.x;
  int lane = t & 63;
  int w = t >> 6, wr = w >> 1, wc = w & 1;
  int la = lane & 15, lg = lane >> 4;
  int rowBase = blockIdx.x * 128;
  int colBase = blockIdx.y * 128;
  const unsigned short* Ab = A + (size_t)(rowBase + (t >> 2)) * K + (t & 3) * 8;
  const unsigned short* Bb = Bw + (size_t)(colBase + (t >> 2)) * K + (t & 3) * 8;

  f32x4 acc[4][4];
#pragma unroll
  for (int i = 0; i < 4; ++i)
#pragma unroll
    for (int j = 0; j < 4; ++j) acc[i][j] = (f32x4){0.f, 0.f, 0.f, 0.f};

  for (int k0 = 0; k0 < K; k0 += 32) {
    gl_lds16(Ab + k0, &lds_a[t * 8]);
    gl_lds16(Ab + (size_t)64 * K + k0, &lds_a[2048 + t * 8]);
    gl_lds16(Bb + k0, &lds_b[t * 8]);
    gl_lds16(Bb + (size_t)64 * K + k0, &lds_b[2048 + t * 8]);
    __syncthreads();
    bf16x8 af[4], bfr[4];
#pragma unroll
    for (int mi = 0; mi < 4; ++mi)
      af[mi] = *reinterpret_cast<const bf16x8*>(&lds_a[(wr * 64 + mi * 16 + la) * 32 + lg * 8]);
#pragma unroll
    for (int ni = 0; ni < 4; ++ni)
      bfr[ni] = *reinterpret_cast<const bf16x8*>(&lds_b[(wc * 64 + ni * 16 + la) * 32 + lg * 8]);
#pragma unroll
    for (int mi = 0; mi < 4; ++mi)
#pragma unroll
      for (int ni = 0; ni < 4; ++ni)
        acc[mi][ni] = __builtin_amdgcn_mfma_f32_16x16x32_bf16(af[mi], bfr[ni], acc[mi][ni], 0, 0, 0);
    __syncthreads();
  }

  if (EPI == 0) {
    float* out = (float*)outp;
#pragma unroll
    for (int mi = 0; mi < 4; ++mi)
#pragma unroll
      for (int ni = 0; ni < 4; ++ni)
#pragma unroll
        for (int j = 0; j < 4; ++j) {
          int row = rowBase + wr * 64 + mi * 16 + lg * 4 + j;
          int col = colBase + wc * 64 + ni * 16 + la;
          out[(size_t)row * N + col] = acc[mi][ni][j];
        }
  } else {
    // Q,K: [which][b,h,s,d].  V: transposed [b,h,d,s].
    unsigned short* qkv = (unsigned short*)outp;
#pragma unroll
    for (int mi = 0; mi < 4; ++mi)
#pragma unroll
      for (int ni = 0; ni < 4; ++ni)
#pragma unroll
        for (int j = 0; j < 4; ++j) {
          int row = rowBase + wr * 64 + mi * 16 + lg * 4 + j;
          int col = colBase + wc * 64 + ni * 16 + la;
          int which = col >> 10, d = col & 1023;
          int h = d >> 6, dd = d & 63;
          int b = row >> 11, s = row & 2047;
          size_t off;
          if (which == 2)
            off = (size_t)2 * 8388608 +
                  ((size_t)(b * NHEADS + h) * DK + dd) * SS + s;
          else
            off = (size_t)which * 8388608 +
                  ((size_t)(b * NHEADS + h) * SS + s) * DK + dd;
          qkv[off] = f2b(acc[mi][ni][j]);
        }
  }
}

// ---------------- RoPE in-place; Q additionally scaled by SM_SCALE ---------
__global__ __launch_bounds__(256) void rope_kernel(unsigned short* __restrict__ Q,
                                                   unsigned short* __restrict__ Kk,
                                                   const int* __restrict__ pos) {
  int i = blockIdx.x * 256 + threadIdx.x;  // < 2 * 64 * 2048 * 32 = 8388608
  int pr = i & 31;
  int row = (i >> 5) & 131071;  // bh*2048 + s
  int isK = i >> 22;
  unsigned short* base = isK ? Kk : Q;
  int s = row & 2047;
  float p = (float)pos[s];
  float ang = p * __expf(-(float)pr * 0.2878231366242557f);  // ln(1e4)/32
  float sn, cs;
  sincosf(ang, &sn, &cs);
  float sc = isK ? 1.0f : SM_SCALE;
  unsigned int* pp = reinterpret_cast<unsigned int*>(base + (size_t)row * 64 + pr * 2);
  unsigned int v = *pp;
  float x1 = b2f((unsigned short)(v & 0xffffu));
  float x2 = b2f((unsigned short)(v >> 16));
  float r1 = (x1 * cs - x2 * sn) * sc;
  float r2 = (x1 * sn + x2 * cs) * sc;
  *pp = (unsigned int)f2b(r1) | ((unsigned int)f2b(r2) << 16);
}

// ---------------- flash attention v3 ---------------------------------------
// Swapped QK^T (mfma(K,Q) -> lane holds S^T[16 keys][q=la]): in-lane row
// reduce + 2 shfl_xor; scalar m,l per lane; defer-max rescale (THR=8, exp2
// domain); double-buffered K/V staging via global_load_lds (1 barrier/tile).
static __device__ __forceinline__ void attn_tile(
    const unsigned short* __restrict__ kt, const unsigned short* __restrict__ vt,
    unsigned short* __restrict__ pl, int la, int lg, int kq, bool diag,
    bf16x8 q0, bf16x8 q1, float& m, float& l, f32x4* o) {
  // S^T = K Q^T : per nb, A-frag rows = keys nb*16+la, B-frag rows = q
  f32x4 st[4];
#pragma unroll
  for (int nb = 0; nb < 4; ++nb) {
    int krow = nb * 16 + la;
    bf16x8 k0 = *reinterpret_cast<const bf16x8*>(&kt[krow * 64 + ((lg ^ (krow & 7)) << 3)]);
    bf16x8 k1 = *reinterpret_cast<const bf16x8*>(&kt[krow * 64 + (((4 + lg) ^ (krow & 7)) << 3)]);
    f32x4 s = (f32x4){0.f, 0.f, 0.f, 0.f};
    s = __builtin_amdgcn_mfma_f32_16x16x32_bf16(k0, q0, s, 0, 0, 0);
    s = __builtin_amdgcn_mfma_f32_16x16x32_bf16(k1, q1, s, 0, 0, 0);
    st[nb] = s;
  }
  // lane (la,lg) holds S^T[key = nb*16+lg*4+j][q = la], pre-scaled (Q folded)
  float sv[16];
#pragma unroll
  for (int nb = 0; nb < 4; ++nb)
#pragma unroll
    for (int j = 0; j < 4; ++j) {
      float v = st[nb][j];
      if (diag && (nb * 16 + j) > kq) v = -1e30f;  // key_in > q_in
      sv[nb * 4 + j] = v;
    }
  float tm = sv[0];
#pragma unroll
  for (int i = 1; i < 16; ++i) tm = fmaxf(tm, sv[i]);
  tm = fmaxf(tm, __shfl_xor(tm, 16));
  tm = fmaxf(tm, __shfl_xor(tm, 32));
  // defer-max: only rescale when tile max grows past m + 8 (exp2 units)
  if (!__all(tm <= m + 8.0f)) {
    float mnew = fmaxf(m, tm);
    float corr = exp2f(m - mnew);
    m = mnew;
    l *= corr;
#pragma unroll
    for (int j = 0; j < 4; ++j) {
      float cj = __shfl(corr, lg * 4 + j);  // stats for q-row lg*4+j live in lane lg*4+j
#pragma unroll
      for (int db = 0; db < 4; ++db) o[db][j] *= cj;
    }
  }
  float rs = 0.f;
  unsigned int pk[8];
#pragma unroll
  for (int i = 0; i < 8; ++i) {
    float p0 = exp2f(sv[2 * i] - m);
    float p1 = exp2f(sv[2 * i + 1] - m);
    rs += p0 + p1;
    pk[i] = (unsigned int)f2b(p0) | ((unsigned int)f2b(p1) << 16);
  }
  rs += __shfl_xor(rs, 16);
  rs += __shfl_xor(rs, 32);
  l += rs;
  // P^T regs -> P[q][key] in LDS (4 x ds_write_b64), then PV
#pragma unroll
  for (int nb = 0; nb < 4; ++nb) {
    uint2 wv;
    wv.x = pk[nb * 2];
    wv.y = pk[nb * 2 + 1];
    *reinterpret_cast<uint2*>(&pl[la * 72 + nb * 16 + lg * 4]) = wv;
  }
#pragma unroll
  for (int kk = 0; kk < 2; ++kk) {
    bf16x8 pa = *reinterpret_cast<const bf16x8*>(&pl[la * 72 + kk * 32 + lg * 8]);
#pragma unroll
    for (int db = 0; db < 4; ++db) {
      int vrow = db * 16 + la;
      bf16x8 vb = *reinterpret_cast<const bf16x8*>(&vt[vrow * 64 + (((kk * 4 + lg) ^ (vrow & 7)) << 3)]);
      o[db] = __builtin_amdgcn_mfma_f32_16x16x32_bf16(pa, vb, o[db], 0, 0, 0);
    }
  }
}

__global__ __launch_bounds__(256) void attn_kernel(const unsigned short* __restrict__ Qh,
                                                   const unsigned short* __restrict__ Kh,
                                                   const unsigned short* __restrict__ Vt,
                                                   unsigned short* __restrict__ outA) {
  __shared__ unsigned short kbuf[2][4096];
  __shared__ unsigned short vbuf[2][4096];
  __shared__ unsigned short plds[4][16 * 72];
  int p = blockIdx.x, bh = blockIdx.y;
  int qtA = p, qtB = 31 - p;
  int t = threadIdx.x, lane = t & 63, w = t >> 6;
  int la = lane & 15, lg = lane >> 4;
  int kq = w * 16 + la - lg * 4;
  const unsigned short* Qp = Qh + (size_t)bh * SS * DK;
  const unsigned short* Kp = Kh + (size_t)bh * SS * DK;
  const unsigned short* Vtp = Vt + (size_t)bh * DK * SS;
  unsigned short* plw = plds[w];

  int qrA = qtA * 64 + w * 16;
  int qrB = qtB * 64 + w * 16;
  bf16x8 qA0 = *reinterpret_cast<const bf16x8*>(Qp + (size_t)(qrA + la) * 64 + lg * 8);
  bf16x8 qA1 = *reinterpret_cast<const bf16x8*>(Qp + (size_t)(qrA + la) * 64 + 32 + lg * 8);
  bf16x8 qB0 = *reinterpret_cast<const bf16x8*>(Qp + (size_t)(qrB + la) * 64 + lg * 8);
  bf16x8 qB1 = *reinterpret_cast<const bf16x8*>(Qp + (size_t)(qrB + la) * 64 + 32 + lg * 8);

  f32x4 oA[4], oB[4];
#pragma unroll
  for (int i = 0; i < 4; ++i) {
    oA[i] = (f32x4){0.f, 0.f, 0.f, 0.f};
    oB[i] = (f32x4){0.f, 0.f, 0.f, 0.f};
  }
  float mA = -1e30f, lA = 0.f, mB = -1e30f, lB = 0.f;

  int c8 = t & 7, r0 = t >> 3;
  auto stage = [&](int bi, int kv) {
    int kvBase = kv * 64;
#pragma unroll
    for (int i = 0; i < 2; ++i) {
      int r = r0 + i * 32;
      gl_lds16(Kp + (size_t)(kvBase + r) * 64 + ((c8 ^ (r & 7)) << 3),
               &kbuf[bi][t * 8 + i * 2048]);
      gl_lds16(Vtp + (size_t)r * SS + kvBase + ((c8 ^ (r & 7)) << 3),
               &vbuf[bi][t * 8 + i * 2048]);
    }
  };

  stage(0, 0);
  __syncthreads();  // drains vmcnt before barrier (compiler-inserted)
  int cur = 0;
  for (int kv = 0; kv <= qtB; ++kv) {
    if (kv < qtB) stage(cur ^ 1, kv + 1);  // prefetch next tile (hidden under compute)
    attn_tile(kbuf[cur], vbuf[cur], plw, la, lg, kq, kv == qtB, qB0, qB1, mB, lB, oB);
    if (kv <= qtA)
      attn_tile(kbuf[cur], vbuf[cur], plw, la, lg, kq, kv == qtA, qA0, qA1, mA, lA, oA);
    __syncthreads();  // waits prefetch + all waves done reading buf[cur]
    cur ^= 1;
  }

  // epilogue: normalize, write bf16 to (b, s, h*64+d) for final GEMM
  int b = bh >> 4, h = bh & 15;
#pragma unroll
  for (int j = 0; j < 4; ++j) {
    float ljB = __shfl(lB, lg * 4 + j);
    float ljA = __shfl(lA, lg * 4 + j);
    float riB = 1.0f / ljB, riA = 1.0f / ljA;
    int qB_ = qrB + lg * 4 + j;
    int qA_ = qrA + lg * 4 + j;
#pragma unroll
    for (int db = 0; db < 4; ++db) {
      outA[((size_t)(b * SS + qB_)) * D_MODEL + h * DK + db * 16 + la] = f2b(oB[db][j] * riB);
      outA[((size_t)(b * SS + qA_)) * D_MODEL + h * DK + db * 16 + la] = f2b(oA[db][j] * riA);
    }
  }
}

extern "C" void kernel_launch(void* const* d_in, const int* in_sizes, int n_in,
                              void* d_out, int out_size, void* d_ws, size_t ws_size,
                              hipStream_t stream) {
  (void)in_sizes; (void)n_in; (void)out_size; (void)ws_size;
  const float* x  = (const float*)d_in[0];
  const float* Wq = (const float*)d_in[1];
  const float* Wk = (const float*)d_in[2];
  const float* Wv = (const float*)d_in[3];
  const float* Wo = (const float*)d_in[4];
  const int* pos  = (const int*)d_in[5];

  char* ws = (char*)d_ws;
  unsigned short* xb    = (unsigned short*)(ws);               // 16 MB: x bf16 [8192][1024]
  unsigned short* Wcat  = (unsigned short*)(ws + 16777216);    // 6 MB: Wq|Wk|Wv rows, then 2 MB Wo
  unsigned short* Qh    = (unsigned short*)(ws + 25165824);    // Q,K (b,h,s,d); V^T (b,h,d,s)
  unsigned short* attnO = (unsigned short*)(ws + 75497472);    // 16 MB: (b,s,1024) bf16

  cast_kernel<<<8192, 256, 0, stream>>>(x, xb, 2097152);
  cast4_kernel<<<4096, 256, 0, stream>>>(Wq, Wk, Wv, Wo, Wcat);

  gemm_bt<1><<<dim3(64, 24), 256, 0, stream>>>(xb, Wcat, Qh, 3072);
  rope_kernel<<<32768, 256, 0, stream>>>(Qh, Qh + 8388608, pos);
  attn_kernel<<<dim3(16, 64), 256, 0, stream>>>(Qh, Qh + 8388608, Qh + 16777216, attnO);
  gemm_bt<0><<<dim3(64, 8), 256, 0, stream>>>(attnO, Wcat + 3145728, (float*)d_out, 1024);
}